// Round 7
// baseline (168.794 us; speedup 1.0000x reference)
//
#include <hip/hip_runtime.h>
#include <hip/hip_fp16.h>
#include <cstddef>
#include <cstdint>

// Sinkformer attention, B=2 H=12 S=1024 D=64, fp32 in/out.
// Flash-recompute Sinkhorn, v3: P never materialized; Q/K/V pre-converted to
// fp16 once (Q16,K16 row-major; Vt16 transposed [h][d][s]). MFMA fragments are
// loaded DIRECTLY from global (L2-resident per XCD via head-grouped swizzle):
// no LDS staging, no barriers in the sweeps; k_final keeps only the 16x136
// ps16 bounce for the P->PV fragment transpose.
//   rd0=rowsum(P); cs0=colsum(P^T a1); rd1=P b1; cs1=colsum(P^T a2);
//   rd2=P b2; cs2=colsum(P^T a3); attn = P*a3*(1/cs2); out = attn @ V.

#define NH 24
#define SEQ 1024
#define HD 64
#define NHS (NH * SEQ)

typedef _Float16 f16x8 __attribute__((ext_vector_type(8)));
typedef float f32x4 __attribute__((ext_vector_type(4)));

// prep: flat grid 2304 = 3*768. z=0: Q->Q16 (+zero the 6 reduce vectors),
// z=1: K->K16, z=2: V->Vt16 (transpose via LDS).
__global__ __launch_bounds__(256) void k_prep(const float* __restrict__ q,
                                              const float* __restrict__ kin,
                                              const float* __restrict__ v,
                                              __half* __restrict__ q16,
                                              __half* __restrict__ k16,
                                              __half* __restrict__ vt16,
                                              float* __restrict__ zvec) {
  const int b = blockIdx.x;
  const int z = b / 768;
  const int bb = b - z * 768;
  const int t = threadIdx.x;
  if (z < 2) {
    const float* src = z ? kin : q;
    __half* dst = z ? k16 : q16;
    size_t u = ((size_t)bb * 256 + t) * 8;
    const float4* s4 = (const float4*)(src + u);
    float4 a = s4[0], c = s4[1];
    f16x8 h;
    h[0] = (_Float16)a.x; h[1] = (_Float16)a.y; h[2] = (_Float16)a.z; h[3] = (_Float16)a.w;
    h[4] = (_Float16)c.x; h[5] = (_Float16)c.y; h[6] = (_Float16)c.z; h[7] = (_Float16)c.w;
    *(f16x8*)(dst + u) = h;
    if (z == 0) {
      int gid = bb * 256 + t;
      if (gid < 6 * NHS) zvec[gid] = 0.f;
    }
  } else {
    __shared__ float ld[64][33];
    const int h = bb >> 5, s0 = (bb & 31) << 5;  // 32-row slab of V
    const float* Vh = v + (size_t)h * SEQ * HD;
#pragma unroll
    for (int it = 0; it < 2; ++it) {
      int f = t + (it << 8);
      int r = f >> 4, c4 = (f & 15) << 2;
      float4 vv = *(const float4*)(Vh + (size_t)(s0 + r) * HD + c4);
      ld[c4 + 0][r] = vv.x; ld[c4 + 1][r] = vv.y;
      ld[c4 + 2][r] = vv.z; ld[c4 + 3][r] = vv.w;
    }
    __syncthreads();
    int d = t >> 2, sg = (t & 3) << 3;
    f16x8 h8;
#pragma unroll
    for (int i = 0; i < 8; ++i) h8[i] = (_Float16)ld[d][sg + i];
    *(f16x8*)(vt16 + (size_t)h * HD * SEQ + (size_t)d * SEQ + s0 + sg) = h8;
  }
}

// Recompute-P sweep, stage-free. 128x128 tile, 4 waves of 64x64, frags from global.
// MODE 0: rdOut_i += sum_j P_ij
// MODE 1: rdOut_i += sum_j P_ij * b_j,  b = (1/1024)/vecPrev[col]
// MODE 2: csOut_j += sum_i P_ij * a_i,  a = (1/1024)/vecPrev[row]
template <int MODE>
__global__ __launch_bounds__(256) void k_sweep(const __half* __restrict__ q16,
                                               const __half* __restrict__ k16,
                                               const float* __restrict__ vecPrev,
                                               float* __restrict__ vecOut) {
  __shared__ float ws_[128];
  const int bid = blockIdx.x;
  const int swz = (bid & 7) * 192 + (bid >> 3);   // 1536 % 8 == 0: bijective
  const int h = swz >> 6;
  const int row0 = ((swz >> 3) & 7) << 7;
  const int col0 = (swz & 7) << 7;
  const int t = threadIdx.x;
  if (MODE == 1 && t < 128) ws_[t] = (1.0f / 1024.0f) / vecPrev[h * SEQ + col0 + t];
  if (MODE == 2 && t < 128) ws_[t] = (1.0f / 1024.0f) / vecPrev[h * SEQ + row0 + t];
  if (MODE) __syncthreads();

  const int w = t >> 6, lane = t & 63;
  const int ln = lane & 15, ko = lane >> 4;
  const int rb = (w & 1) << 6, cb = (w >> 1) << 6;
  const __half* qh = q16 + ((size_t)h << 16);
  const __half* kh = k16 + ((size_t)h << 16);
  f32x4 acc[4][4] = {};
#pragma unroll
  for (int kk = 0; kk < 2; ++kk) {
    f16x8 af[4], bf[4];
#pragma unroll
    for (int m = 0; m < 4; ++m)
      af[m] = *(const f16x8*)(qh + (size_t)(row0 + rb + m * 16 + ln) * HD + kk * 32 + ko * 8);
#pragma unroll
    for (int n = 0; n < 4; ++n)
      bf[n] = *(const f16x8*)(kh + (size_t)(col0 + cb + n * 16 + ln) * HD + kk * 32 + ko * 8);
#pragma unroll
    for (int m = 0; m < 4; ++m)
#pragma unroll
      for (int n = 0; n < 4; ++n)
        acc[m][n] = __builtin_amdgcn_mfma_f32_16x16x32_f16(af[m], bf[n], acc[m][n], 0, 0, 0);
  }

#pragma unroll
  for (int m = 0; m < 4; ++m)
#pragma unroll
    for (int n = 0; n < 4; ++n)
#pragma unroll
      for (int r = 0; r < 4; ++r)
        acc[m][n][r] = __expf(acc[m][n][r] * 0.125f);

  if (MODE == 2) {
    float* cs = vecOut + h * SEQ;
#pragma unroll
    for (int n = 0; n < 4; ++n) {
      float s = 0.f;
#pragma unroll
      for (int m = 0; m < 4; ++m)
#pragma unroll
        for (int r = 0; r < 4; ++r)
          s += acc[m][n][r] * ws_[rb + m * 16 + (ko << 2) + r];
      s += __shfl_xor(s, 16);
      s += __shfl_xor(s, 32);
      if (lane < 16) atomicAdd(&cs[col0 + cb + n * 16 + ln], s);
    }
  } else {
    float* rd = vecOut + h * SEQ;
#pragma unroll
    for (int m = 0; m < 4; ++m)
#pragma unroll
      for (int r = 0; r < 4; ++r) {
        float s;
        if (MODE == 1) {
          s = acc[m][0][r] * ws_[cb + ln] + acc[m][1][r] * ws_[cb + 16 + ln]
            + acc[m][2][r] * ws_[cb + 32 + ln] + acc[m][3][r] * ws_[cb + 48 + ln];
        } else {
          s = acc[m][0][r] + acc[m][1][r] + acc[m][2][r] + acc[m][3][r];
        }
        s += __shfl_xor(s, 1, 16); s += __shfl_xor(s, 2, 16);
        s += __shfl_xor(s, 4, 16); s += __shfl_xor(s, 8, 16);
        if (ln == 0) atomicAdd(&rd[row0 + rb + m * 16 + (ko << 2) + r], s);
      }
  }
}

// Final: 16 rows/block, 4 waves. Per 128-col chunk: recompute P (wave w owns
// cols w*32), exp+scale -> ps16, barrier, attn nontemporal write from ps16,
// PV (A from ps16, B from Vt16 global; wave w owns d = w*16..+15), barrier.
__global__ __launch_bounds__(256) void k_final(const __half* __restrict__ q16,
                                               const __half* __restrict__ k16,
                                               const __half* __restrict__ vt16,
                                               const float* __restrict__ rd2,
                                               const float* __restrict__ cs2,
                                               float* __restrict__ attn,
                                               float* __restrict__ out) {
  __shared__ __align__(16) __half ps16[16][136];
  __shared__ float binv[1024];
  __shared__ float a_s[16];
  const int bid = blockIdx.x;
  const int swz = (bid & 7) * 192 + (bid >> 3);   // bijective
  const int h = swz >> 6;
  const int rblk = swz & 63;                      // 64 blocks of 16 rows per head
  const int t = threadIdx.x;
  const int w = t >> 6, lane = t & 63, ln = lane & 15, ko = lane >> 4;

#pragma unroll
  for (int i = 0; i < 4; ++i) {
    int idx = t + (i << 8);
    binv[idx] = 1.0f / cs2[h * SEQ + idx];
  }
  if (t < 16) a_s[t] = (1.0f / 1024.0f) / rd2[h * SEQ + rblk * 16 + t];

  const __half* qh = q16 + ((size_t)h << 16);
  const __half* kh = k16 + ((size_t)h << 16);
  const __half* vth = vt16 + ((size_t)h << 16);
  f16x8 aq[2];
#pragma unroll
  for (int kk = 0; kk < 2; ++kk)
    aq[kk] = *(const f16x8*)(qh + (size_t)(rblk * 16 + ln) * HD + kk * 32 + ko * 8);

  const int cw = w << 5;   // this wave's 32-col QK slice within the chunk
  const int dw = w << 4;   // this wave's 16-d PV slice
  f32x4 acc_o = {};
  __syncthreads();  // binv / a_s ready

  for (int c = 0; c < 8; ++c) {
    const int j0 = c << 7;
    f32x4 sacc[2] = {};
#pragma unroll
    for (int kk = 0; kk < 2; ++kk) {
#pragma unroll
      for (int n = 0; n < 2; ++n) {
        f16x8 bf = *(const f16x8*)(kh + (size_t)(j0 + cw + n * 16 + ln) * HD + kk * 32 + ko * 8);
        sacc[n] = __builtin_amdgcn_mfma_f32_16x16x32_f16(aq[kk], bf, sacc[n], 0, 0, 0);
      }
    }
    // scale -> ps16 (C-frag: row = ko*4+r, col = cw+n*16+ln)
#pragma unroll
    for (int n = 0; n < 2; ++n)
#pragma unroll
      for (int r = 0; r < 4; ++r) {
        int row = (ko << 2) + r;
        int col = cw + n * 16 + ln;
        ps16[row][col] = __float2half(__expf(sacc[n][r] * 0.125f) * a_s[row] * binv[j0 + col]);
      }
    __syncthreads();
    // attn write (nontemporal): thread t covers row t>>4, 8 cols at (t&15)*8
    {
      int arow = t >> 4, cg = (t & 15) << 3;
      f16x8 hv = *(const f16x8*)&ps16[arow][cg];
      f32x4 o0, o1;
#pragma unroll
      for (int i = 0; i < 4; ++i) { o0[i] = (float)hv[i]; o1[i] = (float)hv[4 + i]; }
      float* ap = attn + (size_t)(h * SEQ + rblk * 16 + arow) * SEQ + j0 + cg;
      __builtin_nontemporal_store(o0, (f32x4*)ap);
      __builtin_nontemporal_store(o1, (f32x4*)(ap + 4));
    }
    // PV: A from ps16 (lane ln = row), B from Vt16 global (lane ln = d)
#pragma unroll
    for (int ks = 0; ks < 4; ++ks) {
      f16x8 pa = *(const f16x8*)&ps16[ln][ks * 32 + ko * 8];
      f16x8 bv = *(const f16x8*)(vth + (size_t)(dw + ln) * SEQ + j0 + ks * 32 + ko * 8);
      acc_o = __builtin_amdgcn_mfma_f32_16x16x32_f16(pa, bv, acc_o, 0, 0, 0);
    }
    __syncthreads();
  }

#pragma unroll
  for (int r = 0; r < 4; ++r)
    out[(size_t)(h * SEQ + rblk * 16 + (ko << 2) + r) * HD + dw + ln] = acc_o[r];
}

extern "C" void kernel_launch(void* const* d_in, const int* in_sizes, int n_in,
                              void* d_out, int out_size, void* d_ws, size_t ws_size,
                              hipStream_t stream) {
  const float* q = (const float*)d_in[0];
  const float* k = (const float*)d_in[1];
  const float* v = (const float*)d_in[2];
  (void)in_sizes; (void)n_in; (void)out_size; (void)ws_size;  // mask is all-False

  float* out = (float*)d_out;
  float* attn = out + (size_t)NH * SEQ * HD;  // second tuple output

  float* wsf = (float*)d_ws;   // 6*NHS floats + 3 fp16 tensors (~10 MB; ws >= 50 MB)
  float* rd0 = wsf;
  float* cs0 = wsf + 1 * NHS;
  float* rd1 = wsf + 2 * NHS;
  float* cs1 = wsf + 3 * NHS;
  float* rd2 = wsf + 4 * NHS;
  float* cs2 = wsf + 5 * NHS;
  __half* q16 = (__half*)(wsf + 6 * NHS);
  __half* k16 = q16 + (size_t)NH * SEQ * HD;
  __half* vt16 = k16 + (size_t)NH * SEQ * HD;

  k_prep<<<2304, 256, 0, stream>>>(q, k, v, q16, k16, vt16, wsf);
  k_sweep<0><<<1536, 256, 0, stream>>>(q16, k16, rd0, rd0);   // rd0 = rowsum(P)
  k_sweep<2><<<1536, 256, 0, stream>>>(q16, k16, rd0, cs0);   // cs0 = colsum(P^T a1)
  k_sweep<1><<<1536, 256, 0, stream>>>(q16, k16, cs0, rd1);   // rd1 = P b1
  k_sweep<2><<<1536, 256, 0, stream>>>(q16, k16, rd1, cs1);   // cs1 = colsum(P^T a2)
  k_sweep<1><<<1536, 256, 0, stream>>>(q16, k16, cs1, rd2);   // rd2 = P b2
  k_sweep<2><<<1536, 256, 0, stream>>>(q16, k16, rd2, cs2);   // cs2 = colsum(P^T a3)
  k_final<<<1536, 256, 0, stream>>>(q16, k16, vt16, rd2, cs2, attn, out);
}

// Round 8
// 168.654 us; speedup vs baseline: 1.0008x; 1.0008x over previous
//
#include <hip/hip_runtime.h>
#include <hip/hip_fp16.h>
#include <cstddef>
#include <cstdint>

// Sinkformer attention, B=2 H=12 S=1024 D=64, fp32 in/out.
// Flash-recompute Sinkhorn v4: P never hits HBM. Q/K/V pre-converted fp16 once.
// Each Sinkhorn iteration = ONE k_pair kernel: block owns a 16-row P strip
// (16x1024 fp16 = 33KB, LDS-resident): phase1 computes P once (MFMA, K dbuf),
// row-reduces in-register (rd = P.b, b=1 first iter) -> a = mu/rd locally;
// phase2 re-reads strip from LDS for colsum partials -> atomics.
// P-computes: 3 pairs + 1 final = 4 (was 7).  k_final: NT stores removed
// (r7 evidence: NT amplified WRITE_SIZE 104->153 MB).
//   pairA: b=1        -> a1, cs0 ;  pairB: b1=nu/cs0 -> a2, cs1
//   pairC: b2=nu/cs1  -> a3, cs2 ;  final: attn = P*a3*(1/cs2); out = attn@V.

#define NH 24
#define SEQ 1024
#define HD 64
#define NHS (NH * SEQ)

typedef _Float16 f16x8 __attribute__((ext_vector_type(8)));
typedef float f32x4 __attribute__((ext_vector_type(4)));

// prep: flat grid 2304 = 3*768. z=0: Q->Q16 (+zero cs0..cs2),
// z=1: K->K16, z=2: V->Vt16 (transpose via LDS).
__global__ __launch_bounds__(256) void k_prep(const float* __restrict__ q,
                                              const float* __restrict__ kin,
                                              const float* __restrict__ v,
                                              __half* __restrict__ q16,
                                              __half* __restrict__ k16,
                                              __half* __restrict__ vt16,
                                              float* __restrict__ zvec) {
  const int b = blockIdx.x;
  const int z = b / 768;
  const int bb = b - z * 768;
  const int t = threadIdx.x;
  if (z < 2) {
    const float* src = z ? kin : q;
    __half* dst = z ? k16 : q16;
    size_t u = ((size_t)bb * 256 + t) * 8;
    const float4* s4 = (const float4*)(src + u);
    float4 a = s4[0], c = s4[1];
    f16x8 h;
    h[0] = (_Float16)a.x; h[1] = (_Float16)a.y; h[2] = (_Float16)a.z; h[3] = (_Float16)a.w;
    h[4] = (_Float16)c.x; h[5] = (_Float16)c.y; h[6] = (_Float16)c.z; h[7] = (_Float16)c.w;
    *(f16x8*)(dst + u) = h;
    if (z == 0) {
      int gid = bb * 256 + t;
      if (gid < 3 * NHS) zvec[gid] = 0.f;  // cs0, cs1, cs2 contiguous
    }
  } else {
    __shared__ float ld[64][33];
    const int h = bb >> 5, s0 = (bb & 31) << 5;  // 32-row slab of V
    const float* Vh = v + (size_t)h * SEQ * HD;
#pragma unroll
    for (int it = 0; it < 2; ++it) {
      int f = t + (it << 8);
      int r = f >> 4, c4 = (f & 15) << 2;
      float4 vv = *(const float4*)(Vh + (size_t)(s0 + r) * HD + c4);
      ld[c4 + 0][r] = vv.x; ld[c4 + 1][r] = vv.y;
      ld[c4 + 2][r] = vv.z; ld[c4 + 3][r] = vv.w;
    }
    __syncthreads();
    int d = t >> 2, sg = (t & 3) << 3;
    f16x8 h8;
#pragma unroll
    for (int i = 0; i < 8; ++i) h8[i] = (_Float16)ld[d][sg + i];
    *(f16x8*)(vt16 + (size_t)h * HD * SEQ + (size_t)d * SEQ + s0 + sg) = h8;
  }
}

// One Sinkhorn iteration. Block = 16-row strip of one head, 4 waves.
// FIRST=1: b=1 (pairA). Else b = (1/1024)/csPrev.
// phase1: P strip -> LDS fp16 + in-register rd = P.b -> a = mu/rd (local).
// phase2: colsum partials from LDS strip -> atomicAdd csOut.
template <int FIRST>
__global__ __launch_bounds__(256) void k_pair(const __half* __restrict__ q16,
                                              const __half* __restrict__ k16,
                                              const float* __restrict__ csPrev,
                                              float* __restrict__ avecOut,
                                              float* __restrict__ csOut) {
  __shared__ __align__(16) __half ps[16][1032];     // 33 KB P strip
  __shared__ __align__(16) __half ks[2][128][72];   // 36 KB K chunk dbuf
  __shared__ float binv[1024];
  __shared__ float rdred[16][4];
  __shared__ float a_s[16];

  const int bid = blockIdx.x;
  const int swz = (bid & 7) * 192 + (bid >> 3);   // 1536 % 8 == 0: bijective
  const int h = swz >> 6;
  const int rblk = swz & 63;                      // 64 strips of 16 rows per head
  const int t = threadIdx.x;
  const int w = t >> 6, lane = t & 63, ln = lane & 15, ko = lane >> 4;

  const __half* qh = q16 + ((size_t)h << 16);
  const __half* kh = k16 + ((size_t)h << 16);

  if (!FIRST) {
#pragma unroll
    for (int i = 0; i < 4; ++i) {
      int idx = t + (i << 8);
      binv[idx] = (1.0f / 1024.0f) / csPrev[h * SEQ + idx];
    }
  }
  // Q frags direct from global (16 rows, L2-hot, read once)
  f16x8 aq[2];
#pragma unroll
  for (int kk = 0; kk < 2; ++kk)
    aq[kk] = *(const f16x8*)(qh + (size_t)(rblk * 16 + ln) * HD + kk * 32 + ko * 8);

  // stage K chunk 0
#pragma unroll
  for (int it = 0; it < 4; ++it) {
    int f = t + (it << 8);
    int row = f >> 3, c8 = (f & 7) << 3;
    *(f16x8*)&ks[0][row][c8] = *(const f16x8*)(kh + (size_t)row * HD + c8);
  }
  __syncthreads();

  const int cw = w << 5;   // wave's 32-col slice within each 128-col chunk
  float rdp[4] = {0.f, 0.f, 0.f, 0.f};

  for (int c = 0; c < 8; ++c) {
    const int buf = c & 1;
    // prefetch next K chunk to regs (hides L2 latency under MFMA)
    f16x8 pre[4];
    if (c < 7) {
#pragma unroll
      for (int it = 0; it < 4; ++it) {
        int f = t + (it << 8);
        int row = f >> 3, c8 = (f & 7) << 3;
        pre[it] = *(const f16x8*)(kh + (size_t)((c + 1) * 128 + row) * HD + c8);
      }
    }
    f32x4 sacc[2] = {};
#pragma unroll
    for (int kk = 0; kk < 2; ++kk)
#pragma unroll
      for (int n = 0; n < 2; ++n) {
        f16x8 bf = *(const f16x8*)&ks[buf][cw + n * 16 + ln][kk * 32 + ko * 8];
        sacc[n] = __builtin_amdgcn_mfma_f32_16x16x32_f16(aq[kk], bf, sacc[n], 0, 0, 0);
      }
    // write prefetch into other buffer (no reader of it until next barrier)
    if (c < 7) {
#pragma unroll
      for (int it = 0; it < 4; ++it) {
        int f = t + (it << 8);
        int row = f >> 3, c8 = (f & 7) << 3;
        *(f16x8*)&ks[buf ^ 1][row][c8] = pre[it];
      }
    }
    // exp -> strip + row-dot partial (C-frag: row = ko*4+r, col = cw+n*16+ln)
#pragma unroll
    for (int n = 0; n < 2; ++n)
#pragma unroll
      for (int r = 0; r < 4; ++r) {
        int row = (ko << 2) + r;
        int col = (c << 7) + cw + n * 16 + ln;
        float p = __expf(sacc[n][r] * 0.125f);
        rdp[r] += FIRST ? p : p * binv[col];
        ps[row][col] = __float2half(p);
      }
    __syncthreads();
  }

  // rd reduce: over ln (16 lanes share rows ko*4+r), then across waves via LDS
#pragma unroll
  for (int r = 0; r < 4; ++r) {
    float s = rdp[r];
    s += __shfl_xor(s, 1, 16); s += __shfl_xor(s, 2, 16);
    s += __shfl_xor(s, 4, 16); s += __shfl_xor(s, 8, 16);
    if (ln == 0) rdred[(ko << 2) + r][w] = s;
  }
  __syncthreads();
  if (t < 16) {
    float rd = rdred[t][0] + rdred[t][1] + rdred[t][2] + rdred[t][3];
    float a = (1.0f / 1024.0f) / rd;
    a_s[t] = a;
    avecOut[h * SEQ + rblk * 16 + t] = a;
  }
  __syncthreads();

  // phase2: colsum partial over the 16 LDS-resident rows; thread t owns 4 cols
  const int c0 = t << 2;
  float cs4[4] = {0.f, 0.f, 0.f, 0.f};
#pragma unroll
  for (int row = 0; row < 16; ++row) {
    uint2 u = *(const uint2*)&ps[row][c0];
    const __half2* hp = (const __half2*)&u;
    float2 f0 = __half22float2(hp[0]), f1 = __half22float2(hp[1]);
    float a = a_s[row];
    cs4[0] += f0.x * a; cs4[1] += f0.y * a;
    cs4[2] += f1.x * a; cs4[3] += f1.y * a;
  }
#pragma unroll
  for (int i = 0; i < 4; ++i) atomicAdd(&csOut[h * SEQ + c0 + i], cs4[i]);
}

// Final: 16 rows/block, 4 waves. Per 128-col chunk: recompute P (wave w owns
// cols w*32), scale by a3*binv -> ps16, barrier, attn write (plain stores),
// PV (A from ps16, B from Vt16 global; wave w owns d = w*16..+15), barrier.
__global__ __launch_bounds__(256) void k_final(const __half* __restrict__ q16,
                                               const __half* __restrict__ k16,
                                               const __half* __restrict__ vt16,
                                               const float* __restrict__ avec,
                                               const float* __restrict__ cs2,
                                               float* __restrict__ attn,
                                               float* __restrict__ out) {
  __shared__ __align__(16) __half ps16[16][136];
  __shared__ float binv[1024];
  __shared__ float a_s[16];
  const int bid = blockIdx.x;
  const int swz = (bid & 7) * 192 + (bid >> 3);   // bijective
  const int h = swz >> 6;
  const int rblk = swz & 63;
  const int t = threadIdx.x;
  const int w = t >> 6, lane = t & 63, ln = lane & 15, ko = lane >> 4;

#pragma unroll
  for (int i = 0; i < 4; ++i) {
    int idx = t + (i << 8);
    binv[idx] = 1.0f / cs2[h * SEQ + idx];
  }
  if (t < 16) a_s[t] = avec[h * SEQ + rblk * 16 + t];

  const __half* qh = q16 + ((size_t)h << 16);
  const __half* kh = k16 + ((size_t)h << 16);
  const __half* vth = vt16 + ((size_t)h << 16);
  f16x8 aq[2];
#pragma unroll
  for (int kk = 0; kk < 2; ++kk)
    aq[kk] = *(const f16x8*)(qh + (size_t)(rblk * 16 + ln) * HD + kk * 32 + ko * 8);

  const int cw = w << 5;   // wave's 32-col QK slice within the chunk
  const int dw = w << 4;   // wave's 16-d PV slice
  f32x4 acc_o = {};
  __syncthreads();  // binv / a_s ready

  for (int c = 0; c < 8; ++c) {
    const int j0 = c << 7;
    f32x4 sacc[2] = {};
#pragma unroll
    for (int kk = 0; kk < 2; ++kk) {
#pragma unroll
      for (int n = 0; n < 2; ++n) {
        f16x8 bf = *(const f16x8*)(kh + (size_t)(j0 + cw + n * 16 + ln) * HD + kk * 32 + ko * 8);
        sacc[n] = __builtin_amdgcn_mfma_f32_16x16x32_f16(aq[kk], bf, sacc[n], 0, 0, 0);
      }
    }
#pragma unroll
    for (int n = 0; n < 2; ++n)
#pragma unroll
      for (int r = 0; r < 4; ++r) {
        int row = (ko << 2) + r;
        int col = cw + n * 16 + ln;
        ps16[row][col] = __float2half(__expf(sacc[n][r] * 0.125f) * a_s[row] * binv[j0 + col]);
      }
    __syncthreads();
    // attn write (plain, L2-combined): thread t covers row t>>4, 8 cols at (t&15)*8
    {
      int arow = t >> 4, cg = (t & 15) << 3;
      f16x8 hv = *(const f16x8*)&ps16[arow][cg];
      f32x4 o0, o1;
#pragma unroll
      for (int i = 0; i < 4; ++i) { o0[i] = (float)hv[i]; o1[i] = (float)hv[4 + i]; }
      float* ap = attn + (size_t)(h * SEQ + rblk * 16 + arow) * SEQ + j0 + cg;
      *(f32x4*)ap = o0;
      *(f32x4*)(ap + 4) = o1;
    }
    // PV: A from ps16 (lane ln = row), B from Vt16 global (lane ln = d)
#pragma unroll
    for (int ks = 0; ks < 4; ++ks) {
      f16x8 pa = *(const f16x8*)&ps16[ln][ks * 32 + ko * 8];
      f16x8 bv = *(const f16x8*)(vth + (size_t)(dw + ln) * SEQ + j0 + ks * 32 + ko * 8);
      acc_o = __builtin_amdgcn_mfma_f32_16x16x32_f16(pa, bv, acc_o, 0, 0, 0);
    }
    __syncthreads();
  }

#pragma unroll
  for (int r = 0; r < 4; ++r)
    out[(size_t)(h * SEQ + rblk * 16 + (ko << 2) + r) * HD + dw + ln] = acc_o[r];
}

extern "C" void kernel_launch(void* const* d_in, const int* in_sizes, int n_in,
                              void* d_out, int out_size, void* d_ws, size_t ws_size,
                              hipStream_t stream) {
  const float* q = (const float*)d_in[0];
  const float* k = (const float*)d_in[1];
  const float* v = (const float*)d_in[2];
  (void)in_sizes; (void)n_in; (void)out_size; (void)ws_size;  // mask is all-False

  float* out = (float*)d_out;
  float* attn = out + (size_t)NH * SEQ * HD;  // second tuple output

  float* wsf = (float*)d_ws;   // 6*NHS floats + 3 fp16 tensors (~10 MB; ws >= 50 MB)
  float* cs0 = wsf;            // zeroed by prep (3*NHS contiguous)
  float* cs1 = wsf + 1 * NHS;
  float* cs2 = wsf + 2 * NHS;
  float* avA = wsf + 3 * NHS;
  float* avB = wsf + 4 * NHS;
  float* avC = wsf + 5 * NHS;
  __half* q16 = (__half*)(wsf + 6 * NHS);
  __half* k16 = q16 + (size_t)NH * SEQ * HD;
  __half* vt16 = k16 + (size_t)NH * SEQ * HD;

  k_prep<<<2304, 256, 0, stream>>>(q, k, v, q16, k16, vt16, wsf);
  k_pair<1><<<1536, 256, 0, stream>>>(q16, k16, cs0, avA, cs0);  // a1, cs0
  k_pair<0><<<1536, 256, 0, stream>>>(q16, k16, cs0, avB, cs1);  // a2, cs1
  k_pair<0><<<1536, 256, 0, stream>>>(q16, k16, cs1, avC, cs2);  // a3, cs2
  k_final<<<1536, 256, 0, stream>>>(q16, k16, vt16, avC, cs2, attn, out);
}

// Round 9
// 136.412 us; speedup vs baseline: 1.2374x; 1.2364x over previous
//
#include <hip/hip_runtime.h>
#include <hip/hip_fp16.h>
#include <cstddef>
#include <cstdint>

// Sinkformer attention, B=2 H=12 S=1024 D=64, fp32 in/out.
// Flash-recompute Sinkhorn v5: P never hits HBM. Q/K/V pre-converted fp16 once.
// 6 r6-style sweeps (one barrier each, K-only LDS staging, Q-frags in regs)
// + pipelined k_final (ps16 dbuf -> 1 barrier/chunk, K/V frag prefetch,
// QK(c+1) overlapped with PV(c)).  r8 evidence: 16-row LDS-strip pairs were
// 3x slower than sweeps (74KB LDS -> 2 blocks/CU, 8 barriers); k_final was
// latency-bound (1.7TB/s write, MfmaUtil 3.6%) with a 2-barrier chunk chain.
//   rd0=rowsum(P); cs0=colsum(P^T a1); rd1=P b1; cs1=colsum(P^T a2);
//   rd2=P b2; cs2=colsum(P^T a3); attn = P*a3*(1/cs2); out = attn @ V.

#define NH 24
#define SEQ 1024
#define HD 64
#define NHS (NH * SEQ)

typedef _Float16 f16x8 __attribute__((ext_vector_type(8)));
typedef float f32x4 __attribute__((ext_vector_type(4)));

// prep: flat grid 2304 = 3*768. z=0: Q->Q16 (+zero rd0..cs2, 6*NHS),
// z=1: K->K16, z=2: V->Vt16 (transpose via LDS).
__global__ __launch_bounds__(256) void k_prep(const float* __restrict__ q,
                                              const float* __restrict__ kin,
                                              const float* __restrict__ v,
                                              __half* __restrict__ q16,
                                              __half* __restrict__ k16,
                                              __half* __restrict__ vt16,
                                              float* __restrict__ zvec) {
  const int b = blockIdx.x;
  const int z = b / 768;
  const int bb = b - z * 768;
  const int t = threadIdx.x;
  if (z < 2) {
    const float* src = z ? kin : q;
    __half* dst = z ? k16 : q16;
    size_t u = ((size_t)bb * 256 + t) * 8;
    const float4* s4 = (const float4*)(src + u);
    float4 a = s4[0], c = s4[1];
    f16x8 h;
    h[0] = (_Float16)a.x; h[1] = (_Float16)a.y; h[2] = (_Float16)a.z; h[3] = (_Float16)a.w;
    h[4] = (_Float16)c.x; h[5] = (_Float16)c.y; h[6] = (_Float16)c.z; h[7] = (_Float16)c.w;
    *(f16x8*)(dst + u) = h;
    if (z == 0) {
      int gid = bb * 256 + t;
      if (gid < 6 * NHS) zvec[gid] = 0.f;  // rd0,cs0,rd1,cs1,rd2,cs2
    }
  } else {
    __shared__ float ld[64][33];
    const int h = bb >> 5, s0 = (bb & 31) << 5;  // 32-row slab of V
    const float* Vh = v + (size_t)h * SEQ * HD;
#pragma unroll
    for (int it = 0; it < 2; ++it) {
      int f = t + (it << 8);
      int r = f >> 4, c4 = (f & 15) << 2;
      float4 vv = *(const float4*)(Vh + (size_t)(s0 + r) * HD + c4);
      ld[c4 + 0][r] = vv.x; ld[c4 + 1][r] = vv.y;
      ld[c4 + 2][r] = vv.z; ld[c4 + 3][r] = vv.w;
    }
    __syncthreads();
    int d = t >> 2, sg = (t & 3) << 3;
    f16x8 h8;
#pragma unroll
    for (int i = 0; i < 8; ++i) h8[i] = (_Float16)ld[d][sg + i];
    *(f16x8*)(vt16 + (size_t)h * HD * SEQ + (size_t)d * SEQ + s0 + sg) = h8;
  }
}

// Recompute-P sweep. 128x128 tile, 4 waves of 64x64. K staged in LDS (18.4KB),
// Q frags held in registers (loaded from L2 once, pre-barrier). One barrier.
// MODE 0: rdOut_i += sum_j P_ij
// MODE 1: rdOut_i += sum_j P_ij * b_j,  b = (1/1024)/vecPrev[col]
// MODE 2: csOut_j += sum_i P_ij * a_i,  a = (1/1024)/vecPrev[row]
template <int MODE>
__global__ __launch_bounds__(256) void k_sweep(const __half* __restrict__ q16,
                                               const __half* __restrict__ k16,
                                               const float* __restrict__ vecPrev,
                                               float* __restrict__ vecOut) {
  __shared__ __align__(16) __half ks[128][72];   // 18.4 KB
  __shared__ float ws_[128];
  const int bid = blockIdx.x;
  const int swz = (bid & 7) * 192 + (bid >> 3);   // 1536 % 8 == 0: bijective
  const int h = swz >> 6;
  const int row0 = ((swz >> 3) & 7) << 7;
  const int col0 = (swz & 7) << 7;
  const int t = threadIdx.x;
  const int w = t >> 6, lane = t & 63;
  const int ln = lane & 15, ko = lane >> 4;
  const int rb = (w & 1) << 6, cb = (w >> 1) << 6;
  const __half* qh = q16 + ((size_t)h << 16);
  const __half* kh = k16 + ((size_t)h << 16);

  // stage K tile (cols of P): 128 rows x 64, f16x8 per thread x4
#pragma unroll
  for (int it = 0; it < 4; ++it) {
    int f = t + (it << 8);
    int row = f >> 3, c8 = (f & 7) << 3;
    *(f16x8*)&ks[row][c8] = *(const f16x8*)(kh + (size_t)(col0 + row) * HD + c8);
  }
  if (MODE == 1 && t < 128) ws_[t] = (1.0f / 1024.0f) / vecPrev[h * SEQ + col0 + t];
  if (MODE == 2 && t < 128) ws_[t] = (1.0f / 1024.0f) / vecPrev[h * SEQ + row0 + t];
  // Q frags direct from global (regs, issued pre-barrier)
  f16x8 af[4][2];
#pragma unroll
  for (int m = 0; m < 4; ++m)
#pragma unroll
    for (int kk = 0; kk < 2; ++kk)
      af[m][kk] = *(const f16x8*)(qh + (size_t)(row0 + rb + m * 16 + ln) * HD + kk * 32 + ko * 8);
  __syncthreads();

  f32x4 acc[4][4] = {};
#pragma unroll
  for (int kk = 0; kk < 2; ++kk) {
    f16x8 bf[4];
#pragma unroll
    for (int n = 0; n < 4; ++n)
      bf[n] = *(const f16x8*)&ks[cb + n * 16 + ln][kk * 32 + ko * 8];
#pragma unroll
    for (int m = 0; m < 4; ++m)
#pragma unroll
      for (int n = 0; n < 4; ++n)
        acc[m][n] = __builtin_amdgcn_mfma_f32_16x16x32_f16(af[m][kk], bf[n], acc[m][n], 0, 0, 0);
  }

#pragma unroll
  for (int m = 0; m < 4; ++m)
#pragma unroll
    for (int n = 0; n < 4; ++n)
#pragma unroll
      for (int r = 0; r < 4; ++r)
        acc[m][n][r] = __expf(acc[m][n][r] * 0.125f);

  if (MODE == 2) {
    float* cs = vecOut + h * SEQ;
#pragma unroll
    for (int n = 0; n < 4; ++n) {
      float s = 0.f;
#pragma unroll
      for (int m = 0; m < 4; ++m)
#pragma unroll
        for (int r = 0; r < 4; ++r)
          s += acc[m][n][r] * ws_[rb + m * 16 + (ko << 2) + r];
      s += __shfl_xor(s, 16);
      s += __shfl_xor(s, 32);
      if (lane < 16) atomicAdd(&cs[col0 + cb + n * 16 + ln], s);
    }
  } else {
    float* rd = vecOut + h * SEQ;
#pragma unroll
    for (int m = 0; m < 4; ++m)
#pragma unroll
      for (int r = 0; r < 4; ++r) {
        float s;
        if (MODE == 1) {
          s = acc[m][0][r] * ws_[cb + ln] + acc[m][1][r] * ws_[cb + 16 + ln]
            + acc[m][2][r] * ws_[cb + 32 + ln] + acc[m][3][r] * ws_[cb + 48 + ln];
        } else {
          s = acc[m][0][r] + acc[m][1][r] + acc[m][2][r] + acc[m][3][r];
        }
        s += __shfl_xor(s, 1, 16); s += __shfl_xor(s, 2, 16);
        s += __shfl_xor(s, 4, 16); s += __shfl_xor(s, 8, 16);
        if (ln == 0) atomicAdd(&rd[row0 + rb + m * 16 + (ko << 2) + r], s);
      }
  }
}

// Final, pipelined: 16 rows/block, 4 waves. Per 128-col chunk (ONE barrier):
//   [prefetch K/V frags c+1] [exp/scale sacc(c) -> ps16[c&1]] BAR
//   [attn store from ps16] [PV(c): A=ps16, B=vf regs] [QK(c+1) -> sacc]
// ps16 dbuf: buffer re-written 2 barriers after its readers -> race-free.
__global__ __launch_bounds__(256) void k_final(const __half* __restrict__ q16,
                                               const __half* __restrict__ k16,
                                               const __half* __restrict__ vt16,
                                               const float* __restrict__ rd2,
                                               const float* __restrict__ cs2,
                                               float* __restrict__ attn,
                                               float* __restrict__ out) {
  __shared__ __align__(16) __half ps16[2][16][136];
  __shared__ float binv[1024];
  __shared__ float a_s[16];
  const int bid = blockIdx.x;
  const int swz = (bid & 7) * 192 + (bid >> 3);   // bijective
  const int h = swz >> 6;
  const int rblk = swz & 63;
  const int t = threadIdx.x;
  const int w = t >> 6, lane = t & 63, ln = lane & 15, ko = lane >> 4;

#pragma unroll
  for (int i = 0; i < 4; ++i) {
    int idx = t + (i << 8);
    binv[idx] = 1.0f / cs2[h * SEQ + idx];
  }
  if (t < 16) a_s[t] = (1.0f / 1024.0f) / rd2[h * SEQ + rblk * 16 + t];

  const __half* qh = q16 + ((size_t)h << 16);
  const __half* kh = k16 + ((size_t)h << 16);
  const __half* vth = vt16 + ((size_t)h << 16);
  f16x8 aq[2];
#pragma unroll
  for (int kk = 0; kk < 2; ++kk)
    aq[kk] = *(const f16x8*)(qh + (size_t)(rblk * 16 + ln) * HD + kk * 32 + ko * 8);

  const int cw = w << 5;   // wave's 32-col QK slice within the chunk
  const int dw = w << 4;   // wave's 16-d PV slice

  // prologue: chunk-0 K and V frags
  f16x8 kf00, kf01, kf10, kf11;  // [kk][n]
  kf00 = *(const f16x8*)(kh + (size_t)(cw + ln) * HD + ko * 8);
  kf01 = *(const f16x8*)(kh + (size_t)(cw + 16 + ln) * HD + ko * 8);
  kf10 = *(const f16x8*)(kh + (size_t)(cw + ln) * HD + 32 + ko * 8);
  kf11 = *(const f16x8*)(kh + (size_t)(cw + 16 + ln) * HD + 32 + ko * 8);
  f16x8 vf0, vf1, vf2, vf3;      // [ks]
  {
    const __half* vb = vth + (size_t)(dw + ln) * SEQ;
    vf0 = *(const f16x8*)(vb + ko * 8);
    vf1 = *(const f16x8*)(vb + 32 + ko * 8);
    vf2 = *(const f16x8*)(vb + 64 + ko * 8);
    vf3 = *(const f16x8*)(vb + 96 + ko * 8);
  }
  f32x4 sacc0 = {}, sacc1 = {};
  sacc0 = __builtin_amdgcn_mfma_f32_16x16x32_f16(aq[0], kf00, sacc0, 0, 0, 0);
  sacc1 = __builtin_amdgcn_mfma_f32_16x16x32_f16(aq[0], kf01, sacc1, 0, 0, 0);
  sacc0 = __builtin_amdgcn_mfma_f32_16x16x32_f16(aq[1], kf10, sacc0, 0, 0, 0);
  sacc1 = __builtin_amdgcn_mfma_f32_16x16x32_f16(aq[1], kf11, sacc1, 0, 0, 0);
  f32x4 acc_o = {};
  __syncthreads();  // binv / a_s ready

  for (int c = 0; c < 8; ++c) {
    const int j0 = c << 7;
    const int buf = c & 1;
    // prefetch next chunk's K and V frags (consumed after the barrier)
    f16x8 kn00, kn01, kn10, kn11, vn0, vn1, vn2, vn3;
    if (c < 7) {
      const __half* kb = kh + (size_t)(j0 + 128) * HD;
      kn00 = *(const f16x8*)(kb + (size_t)(cw + ln) * HD + ko * 8);
      kn01 = *(const f16x8*)(kb + (size_t)(cw + 16 + ln) * HD + ko * 8);
      kn10 = *(const f16x8*)(kb + (size_t)(cw + ln) * HD + 32 + ko * 8);
      kn11 = *(const f16x8*)(kb + (size_t)(cw + 16 + ln) * HD + 32 + ko * 8);
      const __half* vb = vth + (size_t)(dw + ln) * SEQ + j0 + 128;
      vn0 = *(const f16x8*)(vb + ko * 8);
      vn1 = *(const f16x8*)(vb + 32 + ko * 8);
      vn2 = *(const f16x8*)(vb + 64 + ko * 8);
      vn3 = *(const f16x8*)(vb + 96 + ko * 8);
    }
    // exp/scale -> ps16[buf]  (C-frag: row = ko*4+r, col = cw+n*16+ln)
#pragma unroll
    for (int r = 0; r < 4; ++r) {
      int row = (ko << 2) + r;
      int c0 = cw + ln, c1 = cw + 16 + ln;
      ps16[buf][row][c0] = __float2half(__expf(sacc0[r] * 0.125f) * a_s[row] * binv[j0 + c0]);
      ps16[buf][row][c1] = __float2half(__expf(sacc1[r] * 0.125f) * a_s[row] * binv[j0 + c1]);
    }
    __syncthreads();
    // attn store: thread t covers row t>>4, 8 cols at (t&15)*8
    {
      int arow = t >> 4, cg = (t & 15) << 3;
      f16x8 hv = *(const f16x8*)&ps16[buf][arow][cg];
      f32x4 o0, o1;
#pragma unroll
      for (int i = 0; i < 4; ++i) { o0[i] = (float)hv[i]; o1[i] = (float)hv[4 + i]; }
      float* ap = attn + (size_t)(h * SEQ + rblk * 16 + arow) * SEQ + j0 + cg;
      *(f32x4*)ap = o0;
      *(f32x4*)(ap + 4) = o1;
    }
    // PV(c): A from ps16[buf] (lane ln = row), B = vf regs
    {
      f16x8 pa;
      pa = *(const f16x8*)&ps16[buf][ln][ko * 8];
      acc_o = __builtin_amdgcn_mfma_f32_16x16x32_f16(pa, vf0, acc_o, 0, 0, 0);
      pa = *(const f16x8*)&ps16[buf][ln][32 + ko * 8];
      acc_o = __builtin_amdgcn_mfma_f32_16x16x32_f16(pa, vf1, acc_o, 0, 0, 0);
      pa = *(const f16x8*)&ps16[buf][ln][64 + ko * 8];
      acc_o = __builtin_amdgcn_mfma_f32_16x16x32_f16(pa, vf2, acc_o, 0, 0, 0);
      pa = *(const f16x8*)&ps16[buf][ln][96 + ko * 8];
      acc_o = __builtin_amdgcn_mfma_f32_16x16x32_f16(pa, vf3, acc_o, 0, 0, 0);
    }
    // QK(c+1) from prefetched frags; rotate V
    if (c < 7) {
      sacc0 = (f32x4){};
      sacc1 = (f32x4){};
      sacc0 = __builtin_amdgcn_mfma_f32_16x16x32_f16(aq[0], kn00, sacc0, 0, 0, 0);
      sacc1 = __builtin_amdgcn_mfma_f32_16x16x32_f16(aq[0], kn01, sacc1, 0, 0, 0);
      sacc0 = __builtin_amdgcn_mfma_f32_16x16x32_f16(aq[1], kn10, sacc0, 0, 0, 0);
      sacc1 = __builtin_amdgcn_mfma_f32_16x16x32_f16(aq[1], kn11, sacc1, 0, 0, 0);
      vf0 = vn0; vf1 = vn1; vf2 = vn2; vf3 = vn3;
    }
  }

#pragma unroll
  for (int r = 0; r < 4; ++r)
    out[(size_t)(h * SEQ + rblk * 16 + (ko << 2) + r) * HD + dw + ln] = acc_o[r];
}

extern "C" void kernel_launch(void* const* d_in, const int* in_sizes, int n_in,
                              void* d_out, int out_size, void* d_ws, size_t ws_size,
                              hipStream_t stream) {
  const float* q = (const float*)d_in[0];
  const float* k = (const float*)d_in[1];
  const float* v = (const float*)d_in[2];
  (void)in_sizes; (void)n_in; (void)out_size; (void)ws_size;  // mask is all-False

  float* out = (float*)d_out;
  float* attn = out + (size_t)NH * SEQ * HD;  // second tuple output

  float* wsf = (float*)d_ws;   // 6*NHS floats + 3 fp16 tensors (~12 MB)
  float* rd0 = wsf;            // zeroed by prep (6*NHS contiguous)
  float* cs0 = wsf + 1 * NHS;
  float* rd1 = wsf + 2 * NHS;
  float* cs1 = wsf + 3 * NHS;
  float* rd2 = wsf + 4 * NHS;
  float* cs2 = wsf + 5 * NHS;
  __half* q16 = (__half*)(wsf + 6 * NHS);
  __half* k16 = q16 + (size_t)NH * SEQ * HD;
  __half* vt16 = k16 + (size_t)NH * SEQ * HD;

  k_prep<<<2304, 256, 0, stream>>>(q, k, v, q16, k16, vt16, wsf);
  k_sweep<0><<<1536, 256, 0, stream>>>(q16, k16, rd0, rd0);   // rd0 = rowsum(P)
  k_sweep<2><<<1536, 256, 0, stream>>>(q16, k16, rd0, cs0);   // cs0 = colsum(P^T a1)
  k_sweep<1><<<1536, 256, 0, stream>>>(q16, k16, cs0, rd1);   // rd1 = P b1
  k_sweep<2><<<1536, 256, 0, stream>>>(q16, k16, rd1, cs1);   // cs1 = colsum(P^T a2)
  k_sweep<1><<<1536, 256, 0, stream>>>(q16, k16, cs1, rd2);   // rd2 = P b2
  k_sweep<2><<<1536, 256, 0, stream>>>(q16, k16, rd2, cs2);   // cs2 = colsum(P^T a3)
  k_final<<<1536, 256, 0, stream>>>(q16, k16, vt16, rd2, cs2, attn, out);
}